// Round 9
// baseline (254.971 us; speedup 1.0000x reference)
//
#include <hip/hip_runtime.h>
#include <hip/hip_bf16.h>

#define D_MODEL 1024
#define NHEAD   16
#define HDK     64
#define SEQ     2048
#define BATCH   2
#define BS      (BATCH * SEQ)

typedef __attribute__((ext_vector_type(8))) short bf16x8;
typedef __attribute__((ext_vector_type(4))) float f32x4;

__device__ __forceinline__ unsigned short f2bf(float f) {
    unsigned u = __builtin_bit_cast(unsigned, f);
    u += 0x7fffu + ((u >> 16) & 1u);          // round-to-nearest-even
    return (unsigned short)(u >> 16);
}

// RNE-pack two fp32 -> packed bf16x2 dword (low = x, high = y)
__device__ __forceinline__ unsigned pk_rne(float x, float y) {
    return (unsigned)f2bf(x) | ((unsigned)f2bf(y) << 16);
}

// pack hi16(x):hi16(y) with one v_perm_b32 (truncation; used for P in [0,1])
__device__ __forceinline__ unsigned pack_hi(float x, float y) {
    return __builtin_amdgcn_perm(__builtin_bit_cast(unsigned, y),
                                 __builtin_bit_cast(unsigned, x), 0x07060302u);
}

__device__ __forceinline__ float fexp2(float x) {
#if __has_builtin(__builtin_amdgcn_exp2f)
    return __builtin_amdgcn_exp2f(x);
#else
    return exp2f(x);
#endif
}

typedef const void __attribute__((address_space(1))) gas_void;
typedef void __attribute__((address_space(3))) las_void;

__device__ __forceinline__ void gll16(const void* g, void* l) {
    __builtin_amdgcn_global_load_lds((gas_void*)g, (las_void*)l, 16, 0, 0);
}

// ---------------------------------------------------------------------------
// fp32 tile staging into XOR-swizzled bf16 LDS (replaces the cast pass).
// ROWS = 128 or 64. Per group: 8 fp32 loads -> 4 packed dwords -> 1 b128 write.
// ---------------------------------------------------------------------------
template <int ROWS>
__device__ __forceinline__ void stage_f32(const float* __restrict__ X, int ld,
                                          unsigned short* Ls, int t) {
    #pragma unroll
    for (int g = 0; g < ROWS / 32; ++g) {
        int row = (t >> 3) + g * 32;
        int sl  = t & 7;
        int col = (sl ^ (row & 7)) * 8;
        const float4* p = (const float4*)(X + (size_t)row * ld + col);
        float4 a = p[0], b = p[1];
        *(uint4*)&Ls[row * 64 + sl * 8] =
            make_uint4(pk_rne(a.x, a.y), pk_rne(a.z, a.w),
                       pk_rne(b.x, b.y), pk_rne(b.z, b.w));
    }
}

// ---------------------------------------------------------------------------
// Fused Q/K/V projections from fp32 inputs. BM=128 BN=128 BK=64, 256 thr,
// wave -> 64x64 quadrant. z=0: Q (x 0.125*log2e, row-major bf16),
// z=1: K (row-major bf16), z=2: V transposed: VT[(b*16+h)*64+d][s].
// ---------------------------------------------------------------------------
__global__ __launch_bounds__(256)
void proj_gemm(const float* __restrict__ qx, const float* __restrict__ kx,
               const float* __restrict__ vx, const float* __restrict__ wq,
               const float* __restrict__ wk, const float* __restrict__ wv,
               unsigned short* __restrict__ Qp, unsigned short* __restrict__ Kp,
               unsigned short* __restrict__ VT) {
    __shared__ __align__(16) unsigned short As[128 * 64];
    __shared__ __align__(16) unsigned short Bs[128 * 64];

    const int p = blockIdx.z;
    const float* X = p == 0 ? qx : p == 1 ? kx : vx;
    const float* W = p == 0 ? wq : p == 1 ? wk : wv;
    const int bm = blockIdx.y * 128, bn = blockIdx.x * 128;

    const int t    = threadIdx.x;
    const int w    = t >> 6;
    const int L    = t & 63;
    const int quad = L >> 4;
    const int lm   = L & 15;
    const int wr   = (w >> 1) * 64;
    const int wc   = (w & 1) * 64;

    f32x4 acc[4][4];
    #pragma unroll
    for (int ms = 0; ms < 4; ++ms)
        #pragma unroll
        for (int ns = 0; ns < 4; ++ns)
            acc[ms][ns] = (f32x4){0.f, 0.f, 0.f, 0.f};

    for (int kt = 0; kt < D_MODEL; kt += 64) {
        __syncthreads();
        stage_f32<128>(X + (size_t)bm * D_MODEL + kt, D_MODEL, As, t);
        stage_f32<128>(W + (size_t)bn * D_MODEL + kt, D_MODEL, Bs, t);
        __syncthreads();

        #pragma unroll
        for (int ch = 0; ch < 2; ++ch) {
            bf16x8 af[4], bfr[4];
            #pragma unroll
            for (int ms = 0; ms < 4; ++ms) {
                int row = wr + ms * 16 + lm;
                af[ms] = *(const bf16x8*)&As[row * 64 + (((ch * 4 + quad) ^ (row & 7)) * 8)];
            }
            #pragma unroll
            for (int ns = 0; ns < 4; ++ns) {
                int row = wc + ns * 16 + lm;
                bfr[ns] = *(const bf16x8*)&Bs[row * 64 + (((ch * 4 + quad) ^ (row & 7)) * 8)];
            }
            #pragma unroll
            for (int ms = 0; ms < 4; ++ms)
                #pragma unroll
                for (int ns = 0; ns < 4; ++ns)
                    acc[ms][ns] = __builtin_amdgcn_mfma_f32_16x16x32_bf16(
                        af[ms], bfr[ns], acc[ms][ns], 0, 0, 0);
        }
    }

    if (p == 2) {
        const int b    = bm >> 11;
        const int s_in = (bm & (SEQ - 1)) + wr;
        #pragma unroll
        for (int ms = 0; ms < 4; ++ms)
            #pragma unroll
            for (int ns = 0; ns < 4; ++ns) {
                int dg = bn + wc + ns * 16 + lm;
                int h  = dg >> 6, d = dg & 63;
                ushort4 pkv = make_ushort4(f2bf(acc[ms][ns][0]), f2bf(acc[ms][ns][1]),
                                           f2bf(acc[ms][ns][2]), f2bf(acc[ms][ns][3]));
                *(ushort4*)&VT[((size_t)((b * NHEAD + h) * HDK + d)) * SEQ +
                               s_in + ms * 16 + quad * 4] = pkv;
            }
    } else {
        unsigned short* Y = p == 0 ? Qp : Kp;
        // Q scale = 1/sqrt(64) * log2(e)  (softmax in exp2 domain)
        const float scl = p == 0 ? 0.18033688011112042f : 1.0f;
        #pragma unroll
        for (int ms = 0; ms < 4; ++ms)
            #pragma unroll
            for (int ns = 0; ns < 4; ++ns)
                #pragma unroll
                for (int r = 0; r < 4; ++r)
                    Y[(size_t)(bm + wr + ms * 16 + quad * 4 + r) * D_MODEL +
                      bn + wc + ns * 16 + lm] = f2bf(acc[ms][ns][r] * scl);
    }
}

// ---------------------------------------------------------------------------
// out = Ap(bf16) @ Wo(fp32)^T, fp32 out. BM=128 BN=64. A via gll16, W staged
// from fp32.
// ---------------------------------------------------------------------------
__global__ __launch_bounds__(256)
void out_gemm(const unsigned short* __restrict__ X, const float* __restrict__ W,
              float* __restrict__ Y) {
    __shared__ __align__(16) unsigned short As[128 * 64];
    __shared__ __align__(16) unsigned short Bs[64 * 64];
    const int bm = blockIdx.y * 128, bn = blockIdx.x * 64;

    const int t    = threadIdx.x;
    const int w    = t >> 6;
    const int L    = t & 63;
    const int quad = L >> 4;
    const int lm   = L & 15;
    const int r8   = L >> 3;
    const int sl   = L & 7;
    const int xcol = ((sl ^ r8) & 7) * 8;

    f32x4 acc[2][4];
    #pragma unroll
    for (int ms = 0; ms < 2; ++ms)
        #pragma unroll
        for (int ns = 0; ns < 4; ++ns)
            acc[ms][ns] = (f32x4){0.f, 0.f, 0.f, 0.f};

    for (int kt = 0; kt < D_MODEL; kt += 64) {
        __syncthreads();
        #pragma unroll
        for (int i = 0; i < 4; ++i) {
            int c = w * 4 + i;
            gll16(X + (size_t)(bm + c * 8 + r8) * D_MODEL + kt + xcol, &As[c * 512]);
        }
        stage_f32<64>(W + (size_t)bn * D_MODEL + kt, D_MODEL, Bs, t);
        __syncthreads();

        #pragma unroll
        for (int ch = 0; ch < 2; ++ch) {
            bf16x8 af[2], bfr[4];
            #pragma unroll
            for (int ms = 0; ms < 2; ++ms) {
                int row = w * 32 + ms * 16 + lm;
                af[ms] = *(const bf16x8*)&As[row * 64 + (((ch * 4 + quad) ^ (row & 7)) * 8)];
            }
            #pragma unroll
            for (int ns = 0; ns < 4; ++ns) {
                int row = ns * 16 + lm;
                bfr[ns] = *(const bf16x8*)&Bs[row * 64 + (((ch * 4 + quad) ^ (row & 7)) * 8)];
            }
            #pragma unroll
            for (int ms = 0; ms < 2; ++ms)
                #pragma unroll
                for (int ns = 0; ns < 4; ++ns)
                    acc[ms][ns] = __builtin_amdgcn_mfma_f32_16x16x32_bf16(
                        af[ms], bfr[ns], acc[ms][ns], 0, 0, 0);
        }
    }

    #pragma unroll
    for (int ms = 0; ms < 2; ++ms)
        #pragma unroll
        for (int ns = 0; ns < 4; ++ns)
            #pragma unroll
            for (int r = 0; r < 4; ++r)
                Y[(size_t)(bm + w * 32 + ms * 16 + quad * 4 + r) * D_MODEL +
                  bn + ns * 16 + lm] = acc[ms][ns][r];
}

// ---------------------------------------------------------------------------
// Flash attention, causal, S^T form, exp2 domain. 1024 blocks x 256 thr
// (4 waves x 16 q-rows, 64-row q-tile, kv=64). Block f: qt = 31-(f>>5)
// (longest first), bh = f&31 (XCD co-location). Register-prefetch + LDS
// double-buffer -> ONE barrier per tile. Stride-72 LDS (bank-clean).
// Deferred l: per-lane partial, reduced in epilogue. 46 KB LDS -> 3 blk/CU.
// ---------------------------------------------------------------------------
__global__ __launch_bounds__(256)
void attn_mfma(const unsigned short* __restrict__ Q, const unsigned short* __restrict__ K,
               const unsigned short* __restrict__ VT, unsigned short* __restrict__ A) {
    __shared__ __align__(16) unsigned short Ks[2][64 * 72];
    __shared__ __align__(16) unsigned short Vs[2][64 * 72];
    __shared__ __align__(16) unsigned short Ps[4][16 * 72];

    const int t    = threadIdx.x;
    const int w    = t >> 6;
    const int L    = t & 63;
    const int quad = L >> 4;
    const int lm   = L & 15;

    const int f    = blockIdx.x;
    const int qt   = 31 - (f >> 5);
    const int bh   = f & 31;
    const int b    = bh >> 4, h = bh & 15;
    const int q0   = qt * 64;
    const size_t hb  = (size_t)b * SEQ * D_MODEL + h * HDK;
    const size_t vhb = (size_t)(b * NHEAD + h) * HDK;

    const int srow = t >> 2;               // staging row 0..63
    const int sc   = (t & 3) * 16;         // 2x 16B slots per thread
    const unsigned short* kp = K + hb + (size_t)srow * D_MODEL + sc;
    const unsigned short* vp = VT + (vhb + srow) * SEQ + sc;
    unsigned short* ps = &Ps[w][0];

    const int qrow = q0 + w * 16 + lm;
    bf16x8 Qf0, Qf1;
    {
        const unsigned short* qp = Q + hb + (size_t)qrow * D_MODEL + quad * 8;
        Qf0 = *(const bf16x8*)qp;
        Qf1 = *(const bf16x8*)(qp + 32);
    }

    f32x4 Oacc[4];
    #pragma unroll
    for (int nt = 0; nt < 4; ++nt) Oacc[nt] = (f32x4){0.f, 0.f, 0.f, 0.f};
    float m_run = -INFINITY, l_part = 0.f;

    // prologue: tile 0 -> buf 0; prefetch tile 1 into regs
    float4 k0r = *(const float4*)kp;
    float4 k1r = *(const float4*)(kp + 8);
    float4 v0r = *(const float4*)vp;
    float4 v1r = *(const float4*)(vp + 8);
    *(float4*)&Ks[0][srow * 72 + sc]     = k0r;
    *(float4*)&Ks[0][srow * 72 + sc + 8] = k1r;
    *(float4*)&Vs[0][srow * 72 + sc]     = v0r;
    *(float4*)&Vs[0][srow * 72 + sc + 8] = v1r;
    if (qt >= 1) {
        k0r = *(const float4*)(kp + (size_t)64 * D_MODEL);
        k1r = *(const float4*)(kp + (size_t)64 * D_MODEL + 8);
        v0r = *(const float4*)(vp + 64);
        v1r = *(const float4*)(vp + 64 + 8);
    }
    __syncthreads();

    int bb = 0;
    for (int kt = 0; kt <= qt; ++kt) {
        if (kt < qt) {                      // stage kt+1 into other buffer
            unsigned short* Kn = Ks[bb ^ 1];
            unsigned short* Vn = Vs[bb ^ 1];
            *(float4*)&Kn[srow * 72 + sc]     = k0r;
            *(float4*)&Kn[srow * 72 + sc + 8] = k1r;
            *(float4*)&Vn[srow * 72 + sc]     = v0r;
            *(float4*)&Vn[srow * 72 + sc + 8] = v1r;
            if (kt + 2 <= qt) {             // prefetch kt+2 into regs
                k0r = *(const float4*)(kp + (size_t)(kt + 2) * 64 * D_MODEL);
                k1r = *(const float4*)(kp + (size_t)(kt + 2) * 64 * D_MODEL + 8);
                v0r = *(const float4*)(vp + (kt + 2) * 64);
                v1r = *(const float4*)(vp + (kt + 2) * 64 + 8);
            }
        }
        const unsigned short* Kc = Ks[bb];
        const unsigned short* Vc = Vs[bb];

        // ---- S^T = K Q^T (lane owns q-row lm; kv = ct*16+quad*4+r) ----
        f32x4 S[4];
        #pragma unroll
        for (int ct = 0; ct < 4; ++ct) {
            bf16x8 a0 = *(const bf16x8*)&Kc[(ct * 16 + lm) * 72 + quad * 8];
            bf16x8 a1 = *(const bf16x8*)&Kc[(ct * 16 + lm) * 72 + 32 + quad * 8];
            f32x4 z = (f32x4){0.f, 0.f, 0.f, 0.f};
            z = __builtin_amdgcn_mfma_f32_16x16x32_bf16(a0, Qf0, z, 0, 0, 0);
            z = __builtin_amdgcn_mfma_f32_16x16x32_bf16(a1, Qf1, z, 0, 0, 0);
            S[ct] = z;
        }

        if (kt == qt) {                     // causal mask, diag tile only
            #pragma unroll
            for (int ct = 0; ct < 4; ++ct)
                #pragma unroll
                for (int r = 0; r < 4; ++r)
                    if ((q0 + ct * 16 + quad * 4 + r) > qrow)
                        S[ct][r] = -1e30f;
        }

        // ---- online softmax, exp2 domain, deferred-l ----
        float m = fmaxf(fmaxf(fmaxf(S[0][0], S[0][1]), fmaxf(S[0][2], S[0][3])),
                        fmaxf(fmaxf(S[1][0], S[1][1]), fmaxf(S[1][2], S[1][3])));
        m = fmaxf(m, fmaxf(fmaxf(fmaxf(S[2][0], S[2][1]), fmaxf(S[2][2], S[2][3])),
                           fmaxf(fmaxf(S[3][0], S[3][1]), fmaxf(S[3][2], S[3][3]))));
        m = fmaxf(m, __shfl_xor(m, 16));
        m = fmaxf(m, __shfl_xor(m, 32));
        const float m_new = fmaxf(m_run, m);
        const float alpha = fexp2(m_run - m_new);
        m_run = m_new;
        float psum = 0.f;
        #pragma unroll
        for (int ct = 0; ct < 4; ++ct)
            #pragma unroll
            for (int r = 0; r < 4; ++r) {
                float e = fexp2(S[ct][r] - m_new);
                S[ct][r] = e;
                psum += e;
            }
        l_part = l_part * alpha + psum;     // per-lane partial; reduce at end

        // ---- P^T -> wave-private slab (truncation pack), then B-frags ----
        #pragma unroll
        for (int ct = 0; ct < 4; ++ct) {
            uint2 pw = make_uint2(pack_hi(S[ct][0], S[ct][1]),
                                  pack_hi(S[ct][2], S[ct][3]));
            *(uint2*)&ps[lm * 72 + ct * 16 + quad * 4] = pw;
        }
        bf16x8 Pb0 = *(const bf16x8*)&ps[lm * 72 + quad * 8];
        bf16x8 Pb1 = *(const bf16x8*)&ps[lm * 72 + 32 + quad * 8];

        // ---- O^T = O^T*alpha + V^T P^T ----
        #pragma unroll
        for (int nt = 0; nt < 4; ++nt) {
            bf16x8 a0 = *(const bf16x8*)&Vc[(nt * 16 + lm) * 72 + quad * 8];
            bf16x8 a1 = *(const bf16x8*)&Vc[(nt * 16 + lm) * 72 + 32 + quad * 8];
            f32x4 o = Oacc[nt];
            #pragma unroll
            for (int r = 0; r < 4; ++r) o[r] *= alpha;
            o = __builtin_amdgcn_mfma_f32_16x16x32_bf16(a0, Pb0, o, 0, 0, 0);
            o = __builtin_amdgcn_mfma_f32_16x16x32_bf16(a1, Pb1, o, 0, 0, 0);
            Oacc[nt] = o;
        }

        __syncthreads();                    // one barrier per tile
        bb ^= 1;
    }

    // ---- epilogue: reduce l, O^T/l -> slab [q][d] -> coalesced stores ----
    float l = l_part;
    l += __shfl_xor(l, 16);
    l += __shfl_xor(l, 32);
    const float inv_l = 1.f / l;
    #pragma unroll
    for (int nt = 0; nt < 4; ++nt) {
        ushort4 pkv = make_ushort4(f2bf(Oacc[nt][0] * inv_l), f2bf(Oacc[nt][1] * inv_l),
                                   f2bf(Oacc[nt][2] * inv_l), f2bf(Oacc[nt][3] * inv_l));
        *(ushort4*)&ps[lm * 72 + nt * 16 + quad * 4] = pkv;
    }
    #pragma unroll
    for (int cc = 0; cc < 2; ++cc) {
        int row = cc * 8 + (L >> 3);
        int seg = L & 7;
        uint4 val = *(const uint4*)&ps[row * 72 + seg * 8];
        *(uint4*)&A[hb + (size_t)(q0 + w * 16 + row) * D_MODEL + seg * 8] = val;
    }
}

// ---------------------------------------------------------------------------
extern "C" void kernel_launch(void* const* d_in, const int* in_sizes, int n_in,
                              void* d_out, int out_size, void* d_ws, size_t ws_size,
                              hipStream_t stream) {
    const float* q  = (const float*)d_in[0];
    const float* k  = (const float*)d_in[1];
    const float* v  = (const float*)d_in[2];
    const float* Wq = (const float*)d_in[4];
    const float* Wk = (const float*)d_in[5];
    const float* Wv = (const float*)d_in[6];
    const float* Wo = (const float*)d_in[7];
    float* out = (float*)d_out;

    char* ws = (char*)d_ws;
    const size_t MB = 1024 * 1024;
    unsigned short* Qp  = (unsigned short*)(ws + 0 * MB);
    unsigned short* Kp  = (unsigned short*)(ws + 8 * MB);
    unsigned short* VTp = (unsigned short*)(ws + 16 * MB);
    unsigned short* Ap  = (unsigned short*)(ws + 24 * MB);

    proj_gemm<<<dim3(D_MODEL / 128, BS / 128, 3), 256, 0, stream>>>(
        q, k, v, Wq, Wk, Wv, Qp, Kp, VTp);

    attn_mfma<<<dim3(1024), 256, 0, stream>>>(Qp, Kp, VTp, Ap);

    out_gemm<<<dim3(D_MODEL / 64, BS / 128), 256, 0, stream>>>(Ap, Wo, out);
}

// Round 10
// 235.178 us; speedup vs baseline: 1.0842x; 1.0842x over previous
//
#include <hip/hip_runtime.h>
#include <hip/hip_bf16.h>

#define D_MODEL 1024
#define NHEAD   16
#define HDK     64
#define SEQ     2048
#define BATCH   2
#define BS      (BATCH * SEQ)

typedef __attribute__((ext_vector_type(8))) short bf16x8;
typedef __attribute__((ext_vector_type(4))) float f32x4;

__device__ __forceinline__ unsigned short f2bf(float f) {
    unsigned u = __builtin_bit_cast(unsigned, f);
    u += 0x7fffu + ((u >> 16) & 1u);          // round-to-nearest-even
    return (unsigned short)(u >> 16);
}

// RNE-pack two fp32 -> packed bf16x2 dword (low = x, high = y)
__device__ __forceinline__ unsigned pk_rne(float x, float y) {
    return (unsigned)f2bf(x) | ((unsigned)f2bf(y) << 16);
}

// pack hi16(x):hi16(y) with one v_perm_b32 (truncation; used for P in [0,1])
__device__ __forceinline__ unsigned pack_hi(float x, float y) {
    return __builtin_amdgcn_perm(__builtin_bit_cast(unsigned, y),
                                 __builtin_bit_cast(unsigned, x), 0x07060302u);
}

__device__ __forceinline__ float fexp2(float x) {
#if __has_builtin(__builtin_amdgcn_exp2f)
    return __builtin_amdgcn_exp2f(x);
#else
    return exp2f(x);
#endif
}

typedef const void __attribute__((address_space(1))) gas_void;
typedef void __attribute__((address_space(3))) las_void;

__device__ __forceinline__ void gll16(const void* g, void* l) {
    __builtin_amdgcn_global_load_lds((gas_void*)g, (las_void*)l, 16, 0, 0);
}

// ---------------------------------------------------------------------------
// fp32 -> bf16 cast for the 4 weight matrices (16 MB read total, ~5 us)
// ---------------------------------------------------------------------------
__global__ __launch_bounds__(256)
void cast_wt(const float* a, const float* b, const float* c, const float* dd,
             unsigned short* oa, unsigned short* ob, unsigned short* oc,
             unsigned short* od) {
    int i = blockIdx.x * 256 + threadIdx.x;        // 8 elems / thread
    const float* s = blockIdx.y == 0 ? a : blockIdx.y == 1 ? b : blockIdx.y == 2 ? c : dd;
    unsigned short* d = blockIdx.y == 0 ? oa : blockIdx.y == 1 ? ob : blockIdx.y == 2 ? oc : od;
    const float4* p = (const float4*)s + (size_t)i * 2;
    float4 x = p[0], y = p[1];
    uint4 pk = make_uint4(pk_rne(x.x, x.y), pk_rne(x.z, x.w),
                          pk_rne(y.x, y.y), pk_rne(y.z, y.w));
    *((uint4*)d + i) = pk;
}

// ---------------------------------------------------------------------------
// fp32 tile staging into XOR-swizzled bf16 LDS. ROWS = 128.
// ---------------------------------------------------------------------------
template <int ROWS>
__device__ __forceinline__ void stage_f32(const float* __restrict__ X, int ld,
                                          unsigned short* Ls, int t) {
    #pragma unroll
    for (int g = 0; g < ROWS / 32; ++g) {
        int row = (t >> 3) + g * 32;
        int sl  = t & 7;
        int col = (sl ^ (row & 7)) * 8;
        const float4* p = (const float4*)(X + (size_t)row * ld + col);
        float4 a = p[0], b = p[1];
        *(uint4*)&Ls[row * 64 + sl * 8] =
            make_uint4(pk_rne(a.x, a.y), pk_rne(a.z, a.w),
                       pk_rne(b.x, b.y), pk_rne(b.z, b.w));
    }
}

// ---------------------------------------------------------------------------
// Fused Q/K/V projections. 1-D grid 768: z = f>>8, local fl = f&255,
// bm = (fl&7)+8*(fl>>6)  (f%8 == bm%8 -> all 8 bn-blocks of one bm share an
// XCD: X tile fetched once per XCD), bn = (fl>>3)&7. BM=BN=128, BK=64.
// X staged fp32->bf16 in LDS; W (pre-cast bf16) via gll16.
// z=0: Q (x 0.125*log2e), z=1: K, z=2: V transposed VT[(b*16+h)*64+d][s].
// ---------------------------------------------------------------------------
__global__ __launch_bounds__(256)
void proj_gemm(const float* __restrict__ qx, const float* __restrict__ kx,
               const float* __restrict__ vx, const unsigned short* __restrict__ wq,
               const unsigned short* __restrict__ wk, const unsigned short* __restrict__ wv,
               unsigned short* __restrict__ Qp, unsigned short* __restrict__ Kp,
               unsigned short* __restrict__ VT) {
    __shared__ __align__(16) unsigned short As[128 * 64];
    __shared__ __align__(16) unsigned short Bs[128 * 64];

    const int f  = blockIdx.x;
    const int z  = f >> 8;
    const int fl = f & 255;
    const int bm = ((fl & 7) + 8 * (fl >> 6)) * 128;
    const int bn = ((fl >> 3) & 7) * 128;

    const float* X = z == 0 ? qx : z == 1 ? kx : vx;
    const unsigned short* W = z == 0 ? wq : z == 1 ? wk : wv;

    const int t    = threadIdx.x;
    const int w    = t >> 6;
    const int L    = t & 63;
    const int quad = L >> 4;
    const int lm   = L & 15;
    const int r8   = L >> 3;
    const int sl   = L & 7;
    const int xcol = ((sl ^ r8) & 7) * 8;
    const int wr   = (w >> 1) * 64;
    const int wc   = (w & 1) * 64;

    f32x4 acc[4][4];
    #pragma unroll
    for (int ms = 0; ms < 4; ++ms)
        #pragma unroll
        for (int ns = 0; ns < 4; ++ns)
            acc[ms][ns] = (f32x4){0.f, 0.f, 0.f, 0.f};

    for (int kt = 0; kt < D_MODEL; kt += 64) {
        __syncthreads();
        stage_f32<128>(X + (size_t)bm * D_MODEL + kt, D_MODEL, As, t);
        #pragma unroll
        for (int i = 0; i < 4; ++i) {
            int c = w * 4 + i;
            gll16(W + (size_t)(bn + c * 8 + r8) * D_MODEL + kt + xcol, &Bs[c * 512]);
        }
        __syncthreads();

        #pragma unroll
        for (int ch = 0; ch < 2; ++ch) {
            bf16x8 af[4], bfr[4];
            #pragma unroll
            for (int ms = 0; ms < 4; ++ms) {
                int row = wr + ms * 16 + lm;
                af[ms] = *(const bf16x8*)&As[row * 64 + (((ch * 4 + quad) ^ (row & 7)) * 8)];
            }
            #pragma unroll
            for (int ns = 0; ns < 4; ++ns) {
                int row = wc + ns * 16 + lm;
                bfr[ns] = *(const bf16x8*)&Bs[row * 64 + (((ch * 4 + quad) ^ (row & 7)) * 8)];
            }
            #pragma unroll
            for (int ms = 0; ms < 4; ++ms)
                #pragma unroll
                for (int ns = 0; ns < 4; ++ns)
                    acc[ms][ns] = __builtin_amdgcn_mfma_f32_16x16x32_bf16(
                        af[ms], bfr[ns], acc[ms][ns], 0, 0, 0);
        }
    }

    if (z == 2) {
        const int b    = bm >> 11;
        const int s_in = (bm & (SEQ - 1)) + wr;
        #pragma unroll
        for (int ms = 0; ms < 4; ++ms)
            #pragma unroll
            for (int ns = 0; ns < 4; ++ns) {
                int dg = bn + wc + ns * 16 + lm;
                int h  = dg >> 6, d = dg & 63;
                ushort4 pkv = make_ushort4(f2bf(acc[ms][ns][0]), f2bf(acc[ms][ns][1]),
                                           f2bf(acc[ms][ns][2]), f2bf(acc[ms][ns][3]));
                *(ushort4*)&VT[((size_t)((b * NHEAD + h) * HDK + d)) * SEQ +
                               s_in + ms * 16 + quad * 4] = pkv;
            }
    } else {
        unsigned short* Y = z == 0 ? Qp : Kp;
        // Q scale = 1/sqrt(64) * log2(e)  (softmax in exp2 domain)
        const float scl = z == 0 ? 0.18033688011112042f : 1.0f;
        #pragma unroll
        for (int ms = 0; ms < 4; ++ms)
            #pragma unroll
            for (int ns = 0; ns < 4; ++ns)
                #pragma unroll
                for (int r = 0; r < 4; ++r)
                    Y[(size_t)(bm + wr + ms * 16 + quad * 4 + r) * D_MODEL +
                      bn + wc + ns * 16 + lm] = f2bf(acc[ms][ns][r] * scl);
    }
}

// ---------------------------------------------------------------------------
// out = Ap(bf16) @ Wo(bf16)^T, fp32 out. BM=128 BN=64. 1-D grid 512 with the
// same XCD swizzle: bm = (f&7)+8*(f>>7), bn = (f>>3)&15.
// ---------------------------------------------------------------------------
__global__ __launch_bounds__(256)
void out_gemm(const unsigned short* __restrict__ X, const unsigned short* __restrict__ W,
              float* __restrict__ Y) {
    __shared__ __align__(16) unsigned short As[128 * 64];
    __shared__ __align__(16) unsigned short Bs[64 * 64];

    const int f  = blockIdx.x;
    const int bm = ((f & 7) + 8 * (f >> 7)) * 128;
    const int bn = ((f >> 3) & 15) * 64;

    const int t    = threadIdx.x;
    const int w    = t >> 6;
    const int L    = t & 63;
    const int quad = L >> 4;
    const int lm   = L & 15;
    const int r8   = L >> 3;
    const int sl   = L & 7;
    const int xcol = ((sl ^ r8) & 7) * 8;

    f32x4 acc[2][4];
    #pragma unroll
    for (int ms = 0; ms < 2; ++ms)
        #pragma unroll
        for (int ns = 0; ns < 4; ++ns)
            acc[ms][ns] = (f32x4){0.f, 0.f, 0.f, 0.f};

    for (int kt = 0; kt < D_MODEL; kt += 64) {
        __syncthreads();
        #pragma unroll
        for (int i = 0; i < 4; ++i) {
            int c = w * 4 + i;
            gll16(X + (size_t)(bm + c * 8 + r8) * D_MODEL + kt + xcol, &As[c * 512]);
        }
        #pragma unroll
        for (int i = 0; i < 2; ++i) {
            int c = w * 2 + i;
            gll16(W + (size_t)(bn + c * 8 + r8) * D_MODEL + kt + xcol, &Bs[c * 512]);
        }
        __syncthreads();

        #pragma unroll
        for (int ch = 0; ch < 2; ++ch) {
            bf16x8 af[2], bfr[4];
            #pragma unroll
            for (int ms = 0; ms < 2; ++ms) {
                int row = w * 32 + ms * 16 + lm;
                af[ms] = *(const bf16x8*)&As[row * 64 + (((ch * 4 + quad) ^ (row & 7)) * 8)];
            }
            #pragma unroll
            for (int ns = 0; ns < 4; ++ns) {
                int row = ns * 16 + lm;
                bfr[ns] = *(const bf16x8*)&Bs[row * 64 + (((ch * 4 + quad) ^ (row & 7)) * 8)];
            }
            #pragma unroll
            for (int ms = 0; ms < 2; ++ms)
                #pragma unroll
                for (int ns = 0; ns < 4; ++ns)
                    acc[ms][ns] = __builtin_amdgcn_mfma_f32_16x16x32_bf16(
                        af[ms], bfr[ns], acc[ms][ns], 0, 0, 0);
        }
    }

    #pragma unroll
    for (int ms = 0; ms < 2; ++ms)
        #pragma unroll
        for (int ns = 0; ns < 4; ++ns)
            #pragma unroll
            for (int r = 0; r < 4; ++r)
                Y[(size_t)(bm + w * 32 + ms * 16 + quad * 4 + r) * D_MODEL +
                  bn + ns * 16 + lm] = acc[ms][ns][r];
}

// ---------------------------------------------------------------------------
// Flash attention, causal, S^T form, exp2 domain. 1024 blocks x 256 thr
// (4 waves x 16 q-rows, 64-row q-tile, kv=64). Block f: qt = 31-(f>>5)
// (longest first), bh = f&31 (XCD co-location). Register-prefetch + LDS
// double-buffer -> ONE barrier per tile. Stride-72 LDS (bank-clean).
// ---------------------------------------------------------------------------
__global__ __launch_bounds__(256)
void attn_mfma(const unsigned short* __restrict__ Q, const unsigned short* __restrict__ K,
               const unsigned short* __restrict__ VT, unsigned short* __restrict__ A) {
    __shared__ __align__(16) unsigned short Ks[2][64 * 72];
    __shared__ __align__(16) unsigned short Vs[2][64 * 72];
    __shared__ __align__(16) unsigned short Ps[4][16 * 72];

    const int t    = threadIdx.x;
    const int w    = t >> 6;
    const int L    = t & 63;
    const int quad = L >> 4;
    const int lm   = L & 15;

    const int f    = blockIdx.x;
    const int qt   = 31 - (f >> 5);
    const int bh   = f & 31;
    const int b    = bh >> 4, h = bh & 15;
    const int q0   = qt * 64;
    const size_t hb  = (size_t)b * SEQ * D_MODEL + h * HDK;
    const size_t vhb = (size_t)(b * NHEAD + h) * HDK;

    const int srow = t >> 2;               // staging row 0..63
    const int sc   = (t & 3) * 16;         // 2x 16B slots per thread
    const unsigned short* kp = K + hb + (size_t)srow * D_MODEL + sc;
    const unsigned short* vp = VT + (vhb + srow) * SEQ + sc;
    unsigned short* ps = &Ps[w][0];

    const int qrow = q0 + w * 16 + lm;
    bf16x8 Qf0, Qf1;
    {
        const unsigned short* qp = Q + hb + (size_t)qrow * D_MODEL + quad * 8;
        Qf0 = *(const bf16x8*)qp;
        Qf1 = *(const bf16x8*)(qp + 32);
    }

    f32x4 Oacc[4];
    #pragma unroll
    for (int nt = 0; nt < 4; ++nt) Oacc[nt] = (f32x4){0.f, 0.f, 0.f, 0.f};
    float m_run = -INFINITY, l_part = 0.f;

    // prologue: tile 0 -> buf 0; prefetch tile 1 into regs
    float4 k0r = *(const float4*)kp;
    float4 k1r = *(const float4*)(kp + 8);
    float4 v0r = *(const float4*)vp;
    float4 v1r = *(const float4*)(vp + 8);
    *(float4*)&Ks[0][srow * 72 + sc]     = k0r;
    *(float4*)&Ks[0][srow * 72 + sc + 8] = k1r;
    *(float4*)&Vs[0][srow * 72 + sc]     = v0r;
    *(float4*)&Vs[0][srow * 72 + sc + 8] = v1r;
    if (qt >= 1) {
        k0r = *(const float4*)(kp + (size_t)64 * D_MODEL);
        k1r = *(const float4*)(kp + (size_t)64 * D_MODEL + 8);
        v0r = *(const float4*)(vp + 64);
        v1r = *(const float4*)(vp + 64 + 8);
    }
    __syncthreads();

    int bb = 0;
    for (int kt = 0; kt <= qt; ++kt) {
        if (kt < qt) {                      // stage kt+1 into other buffer
            unsigned short* Kn = Ks[bb ^ 1];
            unsigned short* Vn = Vs[bb ^ 1];
            *(float4*)&Kn[srow * 72 + sc]     = k0r;
            *(float4*)&Kn[srow * 72 + sc + 8] = k1r;
            *(float4*)&Vn[srow * 72 + sc]     = v0r;
            *(float4*)&Vn[srow * 72 + sc + 8] = v1r;
            if (kt + 2 <= qt) {             // prefetch kt+2 into regs
                k0r = *(const float4*)(kp + (size_t)(kt + 2) * 64 * D_MODEL);
                k1r = *(const float4*)(kp + (size_t)(kt + 2) * 64 * D_MODEL + 8);
                v0r = *(const float4*)(vp + (kt + 2) * 64);
                v1r = *(const float4*)(vp + (kt + 2) * 64 + 8);
            }
        }
        const unsigned short* Kc = Ks[bb];
        const unsigned short* Vc = Vs[bb];

        // ---- S^T = K Q^T (lane owns q-row lm; kv = ct*16+quad*4+r) ----
        f32x4 S[4];
        #pragma unroll
        for (int ct = 0; ct < 4; ++ct) {
            bf16x8 a0 = *(const bf16x8*)&Kc[(ct * 16 + lm) * 72 + quad * 8];
            bf16x8 a1 = *(const bf16x8*)&Kc[(ct * 16 + lm) * 72 + 32 + quad * 8];
            f32x4 z = (f32x4){0.f, 0.f, 0.f, 0.f};
            z = __builtin_amdgcn_mfma_f32_16x16x32_bf16(a0, Qf0, z, 0, 0, 0);
            z = __builtin_amdgcn_mfma_f32_16x16x32_bf16(a1, Qf1, z, 0, 0, 0);
            S[ct] = z;
        }

        if (kt == qt) {                     // causal mask, diag tile only
            #pragma unroll
            for (int ct = 0; ct < 4; ++ct)
                #pragma unroll
                for (int r = 0; r < 4; ++r)
                    if ((q0 + ct * 16 + quad * 4 + r) > qrow)
                        S[ct][r] = -1e30f;
        }

        // ---- online softmax, exp2 domain, deferred-l ----
        float m = fmaxf(fmaxf(fmaxf(S[0][0], S[0][1]), fmaxf(S[0][2], S[0][3])),
                        fmaxf(fmaxf(S[1][0], S[1][1]), fmaxf(S[1][2], S[1][3])));
        m = fmaxf(m, fmaxf(fmaxf(fmaxf(S[2][0], S[2][1]), fmaxf(S[2][2], S[2][3])),
                           fmaxf(fmaxf(S[3][0], S[3][1]), fmaxf(S[3][2], S[3][3]))));
        m = fmaxf(m, __shfl_xor(m, 16));
        m = fmaxf(m, __shfl_xor(m, 32));
        const float m_new = fmaxf(m_run, m);
        const float alpha = fexp2(m_run - m_new);
        m_run = m_new;
        float psum = 0.f;
        #pragma unroll
        for (int ct = 0; ct < 4; ++ct)
            #pragma unroll
            for (int r = 0; r < 4; ++r) {
                float e = fexp2(S[ct][r] - m_new);
                S[ct][r] = e;
                psum += e;
            }
        l_part = l_part * alpha + psum;     // per-lane partial; reduce at end

        // ---- P^T -> wave-private slab (truncation pack), then B-frags ----
        #pragma unroll
        for (int ct = 0; ct < 4; ++ct) {
            uint2 pw = make_uint2(pack_hi(S[ct][0], S[ct][1]),
                                  pack_hi(S[ct][2], S[ct][3]));
            *(uint2*)&ps[lm * 72 + ct * 16 + quad * 4] = pw;
        }
        bf16x8 Pb0 = *(const bf16x8*)&ps[lm * 72 + quad * 8];
        bf16x8 Pb1 = *(const bf16x8*)&ps[lm * 72 + 32 + quad * 8];

        // ---- O^T = O^T*alpha + V^T P^T ----
        #pragma unroll
        for (int nt = 0; nt < 4; ++nt) {
            bf16x8 a0 = *(const bf16x8*)&Vc[(nt * 16 + lm) * 72 + quad * 8];
            bf16x8 a1 = *(const bf16x8*)&Vc[(nt * 16 + lm) * 72 + 32 + quad * 8];
            f32x4 o = Oacc[nt];
            #pragma unroll
            for (int r = 0; r < 4; ++r) o[r] *= alpha;
            o = __builtin_amdgcn_mfma_f32_16x16x32_bf16(a0, Pb0, o, 0, 0, 0);
            o = __builtin_amdgcn_mfma_f32_16x16x32_bf16(a1, Pb1, o, 0, 0, 0);
            Oacc[nt] = o;
        }

        __syncthreads();                    // one barrier per tile
        bb ^= 1;
    }

    // ---- epilogue: reduce l, O^T/l -> slab [q][d] -> coalesced stores ----
    float l = l_part;
    l += __shfl_xor(l, 16);
    l += __shfl_xor(l, 32);
    const float inv_l = 1.f / l;
    #pragma unroll
    for (int nt = 0; nt < 4; ++nt) {
        ushort4 pkv = make_ushort4(f2bf(Oacc[nt][0] * inv_l), f2bf(Oacc[nt][1] * inv_l),
                                   f2bf(Oacc[nt][2] * inv_l), f2bf(Oacc[nt][3] * inv_l));
        *(ushort4*)&ps[lm * 72 + nt * 16 + quad * 4] = pkv;
    }
    #pragma unroll
    for (int cc = 0; cc < 2; ++cc) {
        int row = cc * 8 + (L >> 3);
        int seg = L & 7;
        uint4 val = *(const uint4*)&ps[row * 72 + seg * 8];
        *(uint4*)&A[hb + (size_t)(q0 + w * 16 + row) * D_MODEL + seg * 8] = val;
    }
}

// ---------------------------------------------------------------------------
extern "C" void kernel_launch(void* const* d_in, const int* in_sizes, int n_in,
                              void* d_out, int out_size, void* d_ws, size_t ws_size,
                              hipStream_t stream) {
    const float* q  = (const float*)d_in[0];
    const float* k  = (const float*)d_in[1];
    const float* v  = (const float*)d_in[2];
    const float* Wq = (const float*)d_in[4];
    const float* Wk = (const float*)d_in[5];
    const float* Wv = (const float*)d_in[6];
    const float* Wo = (const float*)d_in[7];
    float* out = (float*)d_out;

    char* ws = (char*)d_ws;
    const size_t MB = 1024 * 1024;
    unsigned short* wqb = (unsigned short*)(ws + 0 * MB);
    unsigned short* wkb = (unsigned short*)(ws + 2 * MB);
    unsigned short* wvb = (unsigned short*)(ws + 4 * MB);
    unsigned short* wob = (unsigned short*)(ws + 6 * MB);
    unsigned short* Qp  = (unsigned short*)(ws + 8 * MB);
    unsigned short* Kp  = (unsigned short*)(ws + 16 * MB);
    unsigned short* VTp = (unsigned short*)(ws + 24 * MB);
    unsigned short* Ap  = (unsigned short*)(ws + 32 * MB);

    const int nW8 = D_MODEL * D_MODEL / 8;    // 131072
    cast_wt<<<dim3(nW8 / 256, 4), 256, 0, stream>>>(
        Wq, Wk, Wv, Wo, wqb, wkb, wvb, wob);

    proj_gemm<<<dim3(768), 256, 0, stream>>>(q, k, v, wqb, wkb, wvb, Qp, Kp, VTp);

    attn_mfma<<<dim3(1024), 256, 0, stream>>>(Qp, Kp, VTp, Ap);

    out_gemm<<<dim3(512), 256, 0, stream>>>(Ap, wob, out);
}